// Round 3
// baseline (1864.414 us; speedup 1.0000x reference)
//
#include <hip/hip_runtime.h>
#include <math.h>

// ---- problem constants ----
#define BATCH  32
#define NTOK   577
#define CDIM   1024
#define C3DIM  3072
#define H4DIM  4096
#define NHEAD  16
#define MROWS  (BATCH * NTOK)   // 18464

typedef __bf16 bf16x8 __attribute__((ext_vector_type(8)));
typedef float  f32x4  __attribute__((ext_vector_type(4)));
typedef unsigned short u16x8 __attribute__((ext_vector_type(8)));

__device__ __forceinline__ float bf2f(unsigned short u) {
    union { unsigned int i; float f; } v; v.i = ((unsigned int)u) << 16; return v.f;
}
__device__ __forceinline__ unsigned short f2bf(float f) {
    union { float f; unsigned int i; } v; v.f = f;
    unsigned int r = v.i + 0x7FFFu + ((v.i >> 16) & 1u);
    return (unsigned short)(r >> 16);
}
__device__ __forceinline__ bf16x8 ld_bf8(const unsigned short* p) {
    return __builtin_bit_cast(bf16x8, *(const u16x8*)p);
}
// load external scalar (bf16 or f32 storage)
__device__ __forceinline__ float ldx(const void* p, size_t i, bool f32) {
    return f32 ? ((const float*)p)[i] : bf2f(((const unsigned short*)p)[i]);
}
__device__ __forceinline__ uint4 pack8(float4 a, float4 b) {
    uint4 r;
    r.x = (unsigned int)f2bf(a.x) | ((unsigned int)f2bf(a.y) << 16);
    r.y = (unsigned int)f2bf(a.z) | ((unsigned int)f2bf(a.w) << 16);
    r.z = (unsigned int)f2bf(b.x) | ((unsigned int)f2bf(b.y) << 16);
    r.w = (unsigned int)f2bf(b.z) | ((unsigned int)f2bf(b.w) << 16);
    return r;
}

// ---------------- dtype probe: flag=1 if x looks like fp32 data ----------------
__global__ __launch_bounds__(256) void probe_kernel(const unsigned int* __restrict__ x,
                                                    unsigned int* __restrict__ flag) {
    __shared__ int cnt;
    if (threadIdx.x == 0) cnt = 0;
    __syncthreads();
    int c = 0;
#pragma unroll
    for (int i = 0; i < 16; i++) {
        unsigned int w = x[threadIdx.x * 16 + i];
        unsigned int e = (w >> 23) & 0xFFu;
        if (e >= 0x60u && e <= 0x9Eu) c++;   // |v| in [2^-63, 2^64): plausible N(0,1) fp32
    }
    atomicAdd(&cnt, c);
    __syncthreads();
    if (threadIdx.x == 0) *flag = (cnt > 2048) ? 1u : 0u;
}

// ---------------- LayerNorm ----------------
// ext=1: X is an external input (dtype per flag). ext=0: X internal bf16.
__global__ __launch_bounds__(256) void ln_kernel(
    const void* __restrict__ X,
    const void* __restrict__ w,
    const void* __restrict__ b,
    unsigned short* __restrict__ out,
    const unsigned int* __restrict__ dflag, int ext)
{
    const bool f32 = ext && (*dflag != 0);
    const bool wf32 = (*dflag != 0);
    const int row = blockIdx.x;
    const int t = threadIdx.x;
    float vals[4]; float s = 0.f, ss = 0.f;
#pragma unroll
    for (int i = 0; i < 4; i++) {
        int c = t + i * 256;
        float v = ldx(X, (size_t)row * CDIM + c, f32);
        vals[i] = v; s += v; ss += v * v;
    }
#pragma unroll
    for (int off = 32; off > 0; off >>= 1) { s += __shfl_xor(s, off); ss += __shfl_xor(ss, off); }
    __shared__ float red[8];
    if ((t & 63) == 0) { red[t >> 6] = s; red[4 + (t >> 6)] = ss; }
    __syncthreads();
    s  = red[0] + red[1] + red[2] + red[3];
    ss = red[4] + red[5] + red[6] + red[7];
    float mu  = s * (1.f / CDIM);
    float var = ss * (1.f / CDIM) - mu * mu;
    float rs  = rsqrtf(var + 1e-6f);
#pragma unroll
    for (int i = 0; i < 4; i++) {
        int c = t + i * 256;
        float o = (vals[i] - mu) * rs * ldx(w, c, wf32) + ldx(b, c, wf32);
        out[(size_t)row * CDIM + c] = f2bf(o);
    }
}

// ---------------- GEMM: Out = A[M,K]bf16 @ W[N,K]^T + epilogue ----------------
// W/bias external (dtype per flag). A always internal bf16.
// OP=0: +bias, bf16 out.                         (qkv)
// OP=1: +bias, +Res(external x), bf16 out.       (proj -> x1)
// OP=2: +bias, GELU, bf16 out.                   (fc1 chunk)
// OP=3: +bias, +Res(internal bf16 x1), out dtype per flag.   (fc2 chunk 0 -> d_out)
// OP=4: + prior Out (dtype per flag), out dtype per flag.    (fc2 chunks 1..3)
template<int OP>
__global__ __launch_bounds__(256) void gemm_bt(
    const unsigned short* __restrict__ A,
    const void* __restrict__ W, size_t wOff, int Wstride,
    const void* __restrict__ bias, size_t bOff,
    const void* __restrict__ Res,
    void* __restrict__ Out,
    int Mdim, int K, int Nout,
    const unsigned int* __restrict__ dflag)
{
    const bool xf = (*dflag != 0);
    __shared__ __align__(16) unsigned short Alds[128 * 32];
    __shared__ __align__(16) unsigned short Blds[128 * 32];
    const int tid  = threadIdx.x;
    const int lane = tid & 63, wave = tid >> 6;
    const int q = lane >> 4, l16 = lane & 15;
    const int wm = (wave & 1) << 6, wn = (wave >> 1) << 6;
    const int tileM = blockIdx.y << 7, tileN = blockIdx.x << 7;

    f32x4 acc[4][4];
#pragma unroll
    for (int i = 0; i < 4; i++)
#pragma unroll
        for (int j = 0; j < 4; j++) acc[i][j] = (f32x4){0.f, 0.f, 0.f, 0.f};

    const int srow = tid >> 2;
    const int soff = (tid & 3) << 3;
    const unsigned short* Aptr  = A + (size_t)(tileM + srow) * K + soff;
    const unsigned short* Aptr2 = Aptr + (size_t)64 * K;
    const size_t wbase  = wOff + (size_t)(tileN + srow) * Wstride + soff;
    const size_t wbase2 = wbase + (size_t)64 * Wstride;
    const bool a1ok = (tileM + srow) < Mdim;
    const bool a2ok = (tileM + srow + 64) < Mdim;

    for (int k0 = 0; k0 < K; k0 += 32) {
        uint4 av1 = a1ok ? *(const uint4*)(Aptr + k0)  : (uint4){0u, 0u, 0u, 0u};
        uint4 av2 = a2ok ? *(const uint4*)(Aptr2 + k0) : (uint4){0u, 0u, 0u, 0u};
        uint4 bv1, bv2;
        if (!xf) {
            bv1 = *(const uint4*)((const unsigned short*)W + wbase + k0);
            bv2 = *(const uint4*)((const unsigned short*)W + wbase2 + k0);
        } else {
            const float* Wf = (const float*)W;
            float4 lo1 = *(const float4*)(Wf + wbase + k0);
            float4 hi1 = *(const float4*)(Wf + wbase + k0 + 4);
            float4 lo2 = *(const float4*)(Wf + wbase2 + k0);
            float4 hi2 = *(const float4*)(Wf + wbase2 + k0 + 4);
            bv1 = pack8(lo1, hi1);
            bv2 = pack8(lo2, hi2);
        }
        __syncthreads();
        *(uint4*)&Alds[srow * 32 + soff]        = av1;
        *(uint4*)&Alds[(srow + 64) * 32 + soff] = av2;
        *(uint4*)&Blds[srow * 32 + soff]        = bv1;
        *(uint4*)&Blds[(srow + 64) * 32 + soff] = bv2;
        __syncthreads();
        bf16x8 af[4], bfr[4];
#pragma unroll
        for (int mi = 0; mi < 4; mi++) af[mi]  = ld_bf8(&Alds[(wm + mi * 16 + l16) * 32 + q * 8]);
#pragma unroll
        for (int ni = 0; ni < 4; ni++) bfr[ni] = ld_bf8(&Blds[(wn + ni * 16 + l16) * 32 + q * 8]);
#pragma unroll
        for (int mi = 0; mi < 4; mi++)
#pragma unroll
            for (int ni = 0; ni < 4; ni++)
                acc[mi][ni] = __builtin_amdgcn_mfma_f32_16x16x32_bf16(af[mi], bfr[ni], acc[mi][ni], 0, 0, 0);
    }

#pragma unroll
    for (int mi = 0; mi < 4; mi++) {
#pragma unroll
        for (int r = 0; r < 4; r++) {
            int row = tileM + wm + mi * 16 + q * 4 + r;
            if (row >= Mdim) continue;
#pragma unroll
            for (int ni = 0; ni < 4; ni++) {
                int col = tileN + wn + ni * 16 + l16;
                size_t oidx = (size_t)row * Nout + col;
                float v = acc[mi][ni][r];
                if constexpr (OP != 4) v += ldx(bias, bOff + col, xf);
                if constexpr (OP == 2) {
                    v = 0.5f * v * (1.0f + erff(v * 0.70710678118654752f));
                } else if constexpr (OP == 1) {
                    v += ldx(Res, oidx, xf);
                } else if constexpr (OP == 3) {
                    v += bf2f(((const unsigned short*)Res)[oidx]);
                } else if constexpr (OP == 4) {
                    v += xf ? ((const float*)Out)[oidx] : bf2f(((const unsigned short*)Out)[oidx]);
                }
                if constexpr (OP == 3 || OP == 4) {
                    if (xf) ((float*)Out)[oidx] = v;
                    else    ((unsigned short*)Out)[oidx] = f2bf(v);
                } else {
                    ((unsigned short*)Out)[oidx] = f2bf(v);
                }
            }
        }
    }
}

// ---------------- Flash attention ----------------
// qkv: [B, N, 3, H, 64] bf16 (col = s*1024 + h*64 + d). o: [B, N, 1024] bf16.
__global__ __launch_bounds__(256) void attn_kernel(
    const unsigned short* __restrict__ qkv,
    unsigned short* __restrict__ o)
{
    const int bh = blockIdx.y;
    const int b = bh >> 4, h = bh & 15;
    const int q0 = blockIdx.x * 64;
    const int tid = threadIdx.x;
    const int wv = tid >> 6, lane = tid & 63;
    const int qd = lane >> 4, l16 = lane & 15;

    __shared__ __align__(16) unsigned short Qs[64 * 72];
    __shared__ __align__(16) unsigned short Ks[64 * 72];
    __shared__ __align__(16) unsigned short Vt[64 * 72];   // transposed: [d][key]
    __shared__ __align__(16) unsigned short Ps[4][16 * 72];

    const size_t baseQ = ((size_t)b * NTOK) * C3DIM + (size_t)h * 64;

    for (int idx = tid; idx < 64 * 64; idx += 256) {
        int r = idx >> 6, c = idx & 63;
        int gq = q0 + r;
        unsigned short v = 0;
        if (gq < NTOK) v = qkv[baseQ + (size_t)gq * C3DIM + c];
        Qs[r * 72 + c] = v;
    }

    float m_i[4], l_i[4];
    f32x4 Oacc[4];
#pragma unroll
    for (int r = 0; r < 4; r++) { m_i[r] = -1e30f; l_i[r] = 0.f; }
#pragma unroll
    for (int ni = 0; ni < 4; ni++) Oacc[ni] = (f32x4){0.f, 0.f, 0.f, 0.f};

    for (int kt = 0; kt < 10; kt++) {
        const int k0 = kt * 64;
        __syncthreads();
        for (int idx = tid; idx < 64 * 64; idx += 256) {
            int r = idx >> 6, c = idx & 63;
            int gk = k0 + r;
            unsigned short kv = 0, vv = 0;
            if (gk < NTOK) {
                size_t base = ((size_t)b * NTOK + gk) * C3DIM + (size_t)h * 64 + c;
                kv = qkv[base + CDIM];
                vv = qkv[base + 2 * CDIM];
            }
            Ks[r * 72 + c] = kv;
            Vt[c * 72 + r] = vv;
        }
        __syncthreads();

        f32x4 sacc[4];
#pragma unroll
        for (int ni = 0; ni < 4; ni++) sacc[ni] = (f32x4){0.f, 0.f, 0.f, 0.f};
#pragma unroll
        for (int kk = 0; kk < 2; kk++) {
            bf16x8 a = ld_bf8(&Qs[(wv * 16 + l16) * 72 + kk * 32 + qd * 8]);
#pragma unroll
            for (int ni = 0; ni < 4; ni++) {
                bf16x8 bb = ld_bf8(&Ks[(ni * 16 + l16) * 72 + kk * 32 + qd * 8]);
                sacc[ni] = __builtin_amdgcn_mfma_f32_16x16x32_bf16(a, bb, sacc[ni], 0, 0, 0);
            }
        }

#pragma unroll
        for (int r = 0; r < 4; r++) {
            float pv[4];
            float mx = -1e30f;
#pragma unroll
            for (int ni = 0; ni < 4; ni++) {
                float sc = sacc[ni][r] * 0.125f;
                if (k0 + ni * 16 + l16 >= NTOK) sc = -1e30f;
                sacc[ni][r] = sc;
                mx = fmaxf(mx, sc);
            }
#pragma unroll
            for (int off = 8; off > 0; off >>= 1) mx = fmaxf(mx, __shfl_xor(mx, off));
            float mn = fmaxf(m_i[r], mx);
            float alpha = expf(m_i[r] - mn);
            float rsum = 0.f;
#pragma unroll
            for (int ni = 0; ni < 4; ni++) { pv[ni] = expf(sacc[ni][r] - mn); rsum += pv[ni]; }
#pragma unroll
            for (int off = 8; off > 0; off >>= 1) rsum += __shfl_xor(rsum, off);
            l_i[r] = l_i[r] * alpha + rsum;
            m_i[r] = mn;
#pragma unroll
            for (int ni = 0; ni < 4; ni++) {
                Oacc[ni][r] *= alpha;
                Ps[wv][(qd * 4 + r) * 72 + ni * 16 + l16] = f2bf(pv[ni]);
            }
        }
        __syncthreads();

#pragma unroll
        for (int kk = 0; kk < 2; kk++) {
            bf16x8 a = ld_bf8(&Ps[wv][l16 * 72 + kk * 32 + qd * 8]);
#pragma unroll
            for (int ni = 0; ni < 4; ni++) {
                bf16x8 bb = ld_bf8(&Vt[(ni * 16 + l16) * 72 + kk * 32 + qd * 8]);
                Oacc[ni] = __builtin_amdgcn_mfma_f32_16x16x32_bf16(a, bb, Oacc[ni], 0, 0, 0);
            }
        }
    }

#pragma unroll
    for (int r = 0; r < 4; r++) {
        int gq = q0 + wv * 16 + qd * 4 + r;
        if (gq >= NTOK) continue;
        float inv = 1.0f / l_i[r];
#pragma unroll
        for (int ni = 0; ni < 4; ni++) {
            int d = ni * 16 + l16;
            o[((size_t)b * NTOK + gq) * CDIM + (size_t)h * 64 + d] = f2bf(Oacc[ni][r] * inv);
        }
    }
}

// ---------------- launch ----------------
extern "C" void kernel_launch(void* const* d_in, const int* in_sizes, int n_in,
                              void* d_out, int out_size, void* d_ws, size_t ws_size,
                              hipStream_t stream) {
    (void)in_sizes; (void)n_in; (void)out_size; (void)ws_size;
    const void* x      = d_in[0];
    const void* ln1_w  = d_in[1];
    const void* ln1_b  = d_in[2];
    const void* qkv_w  = d_in[3];
    const void* qkv_b  = d_in[4];
    const void* proj_w = d_in[5];
    const void* proj_b = d_in[6];
    const void* ln2_w  = d_in[7];
    const void* ln2_b  = d_in[8];
    const void* fc1_w  = d_in[9];
    const void* fc1_b  = d_in[10];
    const void* fc2_w  = d_in[11];
    const void* fc2_b  = d_in[12];

    // ---- workspace layout (peak 113.4 MB + 256 B) ----
    const size_t szBuf = (size_t)MROWS * CDIM * 2;   // 37,814,272
    char* ws = (char*)d_ws;
    unsigned int*   dflag  = (unsigned int*)ws;
    unsigned short* x1     = (unsigned short*)(ws + 256);             // [M,1024] bf16
    unsigned short* h2     = (unsigned short*)(ws + 256 + szBuf);     // [M,1024] bf16
    unsigned short* gchunk = (unsigned short*)(ws + 256 + 2 * szBuf); // [M,1024] bf16
    unsigned short* qkvb   = (unsigned short*)(ws + 256);             // [M,3072] bf16 overlays x1/h2/gchunk
    unsigned short* hbuf   = (unsigned short*)d_out;                  // LN1 out, then attn out live in d_out
    unsigned short* obuf   = (unsigned short*)d_out;

    const int mt = (MROWS + 127) / 128;  // 145

    probe_kernel<<<1, 256, 0, stream>>>((const unsigned int*)x, dflag);
    // hbuf = LN1(x)            (d_out as scratch)
    ln_kernel<<<MROWS, 256, 0, stream>>>(x, ln1_w, ln1_b, hbuf, dflag, 1);
    // qkvb = hbuf @ qkv_w^T + qkv_b
    gemm_bt<0><<<dim3(C3DIM / 128, mt), 256, 0, stream>>>(
        hbuf, qkv_w, 0, CDIM, qkv_b, 0, nullptr, qkvb, MROWS, CDIM, C3DIM, dflag);
    // obuf = attention(qkvb)   (overwrites hbuf in d_out; hbuf dead)
    attn_kernel<<<dim3(10, BATCH * NHEAD), 256, 0, stream>>>(qkvb, obuf);
    // x1 = bf16(x + obuf @ proj_w^T + proj_b)    (qkvb dead)
    gemm_bt<1><<<dim3(CDIM / 128, mt), 256, 0, stream>>>(
        obuf, proj_w, 0, CDIM, proj_b, 0, x, x1, MROWS, CDIM, CDIM, dflag);
    // h2 = LN2(x1)
    ln_kernel<<<MROWS, 256, 0, stream>>>(x1, ln2_w, ln2_b, h2, dflag, 0);
    // MLP in 4 hidden-chunks of 1024; fc2 accumulates into d_out
    for (int c0 = 0; c0 < H4DIM; c0 += 1024) {
        gemm_bt<2><<<dim3(1024 / 128, mt), 256, 0, stream>>>(
            h2, fc1_w, (size_t)c0 * CDIM, CDIM, fc1_b, c0, nullptr, gchunk, MROWS, CDIM, 1024, dflag);
        if (c0 == 0) {
            gemm_bt<3><<<dim3(CDIM / 128, mt), 256, 0, stream>>>(
                gchunk, fc2_w, 0, H4DIM, fc2_b, 0, x1, d_out, MROWS, CDIM, CDIM, dflag);
        } else {
            gemm_bt<4><<<dim3(CDIM / 128, mt), 256, 0, stream>>>(
                gchunk, fc2_w, c0, H4DIM, nullptr, 0, nullptr, d_out, MROWS, CDIM, CDIM, dflag);
        }
    }
}

// Round 4
// 1515.134 us; speedup vs baseline: 1.2305x; 1.2305x over previous
//
#include <hip/hip_runtime.h>
#include <math.h>

// ---- problem constants ----
#define BATCH  32
#define NTOK   577
#define CDIM   1024
#define C3DIM  3072
#define H4DIM  4096
#define NHEAD  16
#define MROWS  (BATCH * NTOK)   // 18464
#define NPADV  584              // 577 rounded up to 8 (V^T row pad)

typedef __bf16 bf16x8 __attribute__((ext_vector_type(8)));
typedef float  f32x4  __attribute__((ext_vector_type(4)));
typedef unsigned short u16x8 __attribute__((ext_vector_type(8)));

__device__ __forceinline__ float bf2f(unsigned short u) {
    union { unsigned int i; float f; } v; v.i = ((unsigned int)u) << 16; return v.f;
}
__device__ __forceinline__ unsigned short f2bf(float f) {
    union { float f; unsigned int i; } v; v.f = f;
    unsigned int r = v.i + 0x7FFFu + ((v.i >> 16) & 1u);
    return (unsigned short)(r >> 16);
}
__device__ __forceinline__ bf16x8 ld_bf8(const unsigned short* p) {
    return __builtin_bit_cast(bf16x8, *(const u16x8*)p);
}

// async global->LDS, 16B per lane. LDS dest = wave-uniform base + lane*16.
typedef const __attribute__((address_space(1))) unsigned int* gptr_t;
typedef __attribute__((address_space(3))) unsigned int* lptr_t;
__device__ __forceinline__ void gl2lds(const void* g, const void* l) {
    __builtin_amdgcn_global_load_lds(
        (gptr_t)(unsigned long long)g,
        (lptr_t)(unsigned int)(unsigned long long)l,
        16, 0, 0);
}

// ---------------- f32 -> bf16 convert ----------------
__global__ __launch_bounds__(256) void conv_kernel(const float* __restrict__ src,
                                                   unsigned short* __restrict__ dst, int n) {
    int i = (blockIdx.x * 256 + threadIdx.x) * 4;
    if (i < n) {
        float4 v = *(const float4*)(src + i);
        dst[i]     = f2bf(v.x);
        dst[i + 1] = f2bf(v.y);
        dst[i + 2] = f2bf(v.z);
        dst[i + 3] = f2bf(v.w);
    }
}

// ---------------- LayerNorm ----------------
template<bool F32IN>
__global__ __launch_bounds__(256) void ln_kernel(
    const void* __restrict__ X,
    const float* __restrict__ w,
    const float* __restrict__ b,
    unsigned short* __restrict__ out)
{
    const int row = blockIdx.x;
    const int t = threadIdx.x;
    float vals[4]; float s = 0.f, ss = 0.f;
#pragma unroll
    for (int i = 0; i < 4; i++) {
        int c = t + i * 256;
        float v;
        if (F32IN) v = ((const float*)X)[(size_t)row * CDIM + c];
        else       v = bf2f(((const unsigned short*)X)[(size_t)row * CDIM + c]);
        vals[i] = v; s += v; ss += v * v;
    }
#pragma unroll
    for (int off = 32; off > 0; off >>= 1) { s += __shfl_xor(s, off); ss += __shfl_xor(ss, off); }
    __shared__ float red[8];
    if ((t & 63) == 0) { red[t >> 6] = s; red[4 + (t >> 6)] = ss; }
    __syncthreads();
    s  = red[0] + red[1] + red[2] + red[3];
    ss = red[4] + red[5] + red[6] + red[7];
    float mu  = s * (1.f / CDIM);
    float var = ss * (1.f / CDIM) - mu * mu;
    float rs  = rsqrtf(var + 1e-6f);
#pragma unroll
    for (int i = 0; i < 4; i++) {
        int c = t + i * 256;
        float o = (vals[i] - mu) * rs * w[c] + b[c];
        out[(size_t)row * CDIM + c] = f2bf(o);
    }
}

// ---------------- GEMM: Out = A[M,K]bf16 @ W[N,K]bf16^T + epilogue ----------------
// OP=0: +bias, qkv split-scatter (Out=Qb *0.125, Out2=Kb, Out3=Vt transposed)
// OP=1: +bias, + f32 residual (Res=x), bf16 out (x1)
// OP=2: +bias, GELU, bf16 out (fc1 chunk)
// OP=3: +bias, + bf16 residual (x1), f32 out to d_out
// OP=4: f32 accumulate into d_out (no bias)
template<int OP>
__global__ __launch_bounds__(256) void gemm_bt(
    const unsigned short* __restrict__ A,
    const unsigned short* __restrict__ W, int Wstride,
    const unsigned short* __restrict__ bias,
    const void* __restrict__ Res,
    void* __restrict__ Out,
    void* __restrict__ Out2,
    void* __restrict__ Out3,
    int K, int Nout)
{
    __shared__ __align__(16) unsigned short Alds[128 * 32];
    __shared__ __align__(16) unsigned short Blds[128 * 32];
    const int tid  = threadIdx.x;
    const int lane = tid & 63, wave = tid >> 6;
    const int q = lane >> 4, l16 = lane & 15;
    const int wm = (wave & 1) << 6, wn = (wave >> 1) << 6;
    const int tileM = blockIdx.y << 7, tileN = blockIdx.x << 7;

    f32x4 acc[4][4];
#pragma unroll
    for (int i = 0; i < 4; i++)
#pragma unroll
        for (int j = 0; j < 4; j++) acc[i][j] = (f32x4){0.f, 0.f, 0.f, 0.f};

    const int srow = tid >> 2;
    const int soff = (tid & 3) << 3;
    int arow1 = tileM + srow;       if (arow1 > MROWS - 1) arow1 = MROWS - 1;
    int arow2 = tileM + srow + 64;  if (arow2 > MROWS - 1) arow2 = MROWS - 1;
    const unsigned short* Aptr  = A + (size_t)arow1 * K + soff;
    const unsigned short* Aptr2 = A + (size_t)arow2 * K + soff;
    const unsigned short* Wp    = W + (size_t)(tileN + srow) * Wstride + soff;
    const unsigned short* Wp2   = Wp + (size_t)64 * Wstride;

    for (int k0 = 0; k0 < K; k0 += 32) {
        __syncthreads();   // all reads of previous tile complete
        gl2lds(Aptr  + k0, &Alds[wave * 512]);
        gl2lds(Aptr2 + k0, &Alds[2048 + wave * 512]);
        gl2lds(Wp    + k0, &Blds[wave * 512]);
        gl2lds(Wp2   + k0, &Blds[2048 + wave * 512]);
        __syncthreads();   // drains vmcnt -> LDS populated
        bf16x8 af[4], bfr[4];
#pragma unroll
        for (int mi = 0; mi < 4; mi++) af[mi]  = ld_bf8(&Alds[(wm + mi * 16 + l16) * 32 + q * 8]);
#pragma unroll
        for (int ni = 0; ni < 4; ni++) bfr[ni] = ld_bf8(&Blds[(wn + ni * 16 + l16) * 32 + q * 8]);
#pragma unroll
        for (int mi = 0; mi < 4; mi++)
#pragma unroll
            for (int ni = 0; ni < 4; ni++)
                acc[mi][ni] = __builtin_amdgcn_mfma_f32_16x16x32_bf16(af[mi], bfr[ni], acc[mi][ni], 0, 0, 0);
    }

#pragma unroll
    for (int mi = 0; mi < 4; mi++) {
#pragma unroll
        for (int r = 0; r < 4; r++) {
            int row = tileM + wm + mi * 16 + q * 4 + r;
            if (row >= MROWS) continue;
            unsigned int bb = 0, nn = 0;
            if constexpr (OP == 0) {
                bb = ((unsigned int)row * 58154u) >> 25;   // row/577, exact for row<78766
                nn = (unsigned int)row - bb * 577u;
            }
#pragma unroll
            for (int ni = 0; ni < 4; ni++) {
                int col = tileN + wn + ni * 16 + l16;
                size_t oidx = (size_t)row * Nout + col;
                float v = acc[mi][ni][r];
                if constexpr (OP != 4) v += bf2f(bias[col]);
                if constexpr (OP == 0) {
                    int s = col >> 10, h = (col >> 6) & 15, d = col & 63;
                    size_t bh = (size_t)(bb * 16 + h);
                    if (s == 0)      ((unsigned short*)Out )[(bh * NTOK + nn) * 64 + d] = f2bf(v * 0.125f);
                    else if (s == 1) ((unsigned short*)Out2)[(bh * NTOK + nn) * 64 + d] = f2bf(v);
                    else             ((unsigned short*)Out3)[(bh * 64 + d) * NPADV + nn] = f2bf(v);
                } else if constexpr (OP == 1) {
                    v += ((const float*)Res)[oidx];
                    ((unsigned short*)Out)[oidx] = f2bf(v);
                } else if constexpr (OP == 2) {
                    v = 0.5f * v * (1.0f + erff(v * 0.70710678118654752f));
                    ((unsigned short*)Out)[oidx] = f2bf(v);
                } else if constexpr (OP == 3) {
                    v += bf2f(((const unsigned short*)Res)[oidx]);
                    ((float*)Out)[oidx] = v;
                } else {
                    ((float*)Out)[oidx] += v;
                }
            }
        }
    }
}

// ---------------- Flash attention: fragments direct from global ----------------
// Qb,Kb: [B*H, 577, 64] bf16 (Q pre-scaled by 0.125). Vt: [B*H, 64, 584] bf16.
// o: [B,N,1024] bf16.
__global__ __launch_bounds__(256) void attn_kernel(
    const unsigned short* __restrict__ Qb,
    const unsigned short* __restrict__ Kb,
    const unsigned short* __restrict__ Vt,
    unsigned short* __restrict__ o)
{
    const int bh = blockIdx.y;           // b*16 + h
    const int q0 = blockIdx.x * 64;
    const int tid = threadIdx.x;
    const int wv = tid >> 6, lane = tid & 63;
    const int qd = lane >> 4, l16 = lane & 15;

    __shared__ __align__(16) unsigned short Ps[4][16 * 72];

    const unsigned short* Qh = Qb + (size_t)bh * NTOK * 64;
    const unsigned short* Kh = Kb + (size_t)bh * NTOK * 64;
    const unsigned short* Vh = Vt + (size_t)bh * 64 * NPADV;

    int qrow = q0 + wv * 16 + l16;
    int qr = qrow < NTOK ? qrow : NTOK - 1;
    bf16x8 qf0 = ld_bf8(Qh + (size_t)qr * 64 + qd * 8);
    bf16x8 qf1 = ld_bf8(Qh + (size_t)qr * 64 + 32 + qd * 8);

    float m_i[4], l_i[4];
    f32x4 Oacc[4];
#pragma unroll
    for (int r = 0; r < 4; r++) { m_i[r] = -1e30f; l_i[r] = 0.f; }
#pragma unroll
    for (int ni = 0; ni < 4; ni++) Oacc[ni] = (f32x4){0.f, 0.f, 0.f, 0.f};

    for (int kt = 0; kt < 10; kt++) {
        const int k0 = kt * 64;
        f32x4 sacc[4];
#pragma unroll
        for (int ni = 0; ni < 4; ni++) sacc[ni] = (f32x4){0.f, 0.f, 0.f, 0.f};
#pragma unroll
        for (int ni = 0; ni < 4; ni++) {
            int krow = k0 + ni * 16 + l16;
            if (krow > NTOK - 1) krow = NTOK - 1;
            const unsigned short* kp = Kh + (size_t)krow * 64 + qd * 8;
            bf16x8 b0 = ld_bf8(kp);
            bf16x8 b1 = ld_bf8(kp + 32);
            sacc[ni] = __builtin_amdgcn_mfma_f32_16x16x32_bf16(qf0, b0, sacc[ni], 0, 0, 0);
            sacc[ni] = __builtin_amdgcn_mfma_f32_16x16x32_bf16(qf1, b1, sacc[ni], 0, 0, 0);
        }

        // online softmax; lane holds S[row=qd*4+r][key=k0+ni*16+l16]
#pragma unroll
        for (int r = 0; r < 4; r++) {
            float pv[4];
            float mx = -1e30f;
#pragma unroll
            for (int ni = 0; ni < 4; ni++) {
                float sc = sacc[ni][r];
                if (k0 + ni * 16 + l16 >= NTOK) sc = -1e30f;
                sacc[ni][r] = sc;
                mx = fmaxf(mx, sc);
            }
#pragma unroll
            for (int off = 8; off > 0; off >>= 1) mx = fmaxf(mx, __shfl_xor(mx, off));
            float mn = fmaxf(m_i[r], mx);
            float alpha = expf(m_i[r] - mn);
            float rsum = 0.f;
#pragma unroll
            for (int ni = 0; ni < 4; ni++) { pv[ni] = expf(sacc[ni][r] - mn); rsum += pv[ni]; }
#pragma unroll
            for (int off = 8; off > 0; off >>= 1) rsum += __shfl_xor(rsum, off);
            l_i[r] = l_i[r] * alpha + rsum;
            m_i[r] = mn;
#pragma unroll
            for (int ni = 0; ni < 4; ni++) {
                Oacc[ni][r] *= alpha;
                Ps[wv][(qd * 4 + r) * 72 + ni * 16 + l16] = f2bf(pv[ni]);
            }
        }
        // per-wave private LDS region: no barrier needed (lgkmcnt ordering within wave)

        // O += P @ V   (contract over keys; V^T rows = head dims)
#pragma unroll
        for (int kk = 0; kk < 2; kk++) {
            bf16x8 a = ld_bf8(&Ps[wv][l16 * 72 + kk * 32 + qd * 8]);
            int kchunk = k0 + kk * 32 + qd * 8;
            if (kchunk > NTOK - 1) kchunk = NTOK - 1;  // clamped chunks have P==0
#pragma unroll
            for (int ni = 0; ni < 4; ni++) {
                bf16x8 bb = ld_bf8(Vh + (size_t)(ni * 16 + l16) * NPADV + kchunk);
                Oacc[ni] = __builtin_amdgcn_mfma_f32_16x16x32_bf16(a, bb, Oacc[ni], 0, 0, 0);
            }
        }
    }

    const int b = bh >> 4, h = bh & 15;
#pragma unroll
    for (int r = 0; r < 4; r++) {
        int gq = q0 + wv * 16 + qd * 4 + r;
        if (gq >= NTOK) continue;
        float inv = 1.0f / l_i[r];
#pragma unroll
        for (int ni = 0; ni < 4; ni++) {
            int d = ni * 16 + l16;
            o[((size_t)b * NTOK + gq) * CDIM + (size_t)h * 64 + d] = f2bf(Oacc[ni][r] * inv);
        }
    }
}

// ---------------- launch ----------------
extern "C" void kernel_launch(void* const* d_in, const int* in_sizes, int n_in,
                              void* d_out, int out_size, void* d_ws, size_t ws_size,
                              hipStream_t stream) {
    (void)in_sizes; (void)n_in; (void)out_size;
    const float* x      = (const float*)d_in[0];
    const float* ln1_w  = (const float*)d_in[1];
    const float* ln1_b  = (const float*)d_in[2];
    const float* qkv_w  = (const float*)d_in[3];
    const float* qkv_b  = (const float*)d_in[4];
    const float* proj_w = (const float*)d_in[5];
    const float* proj_b = (const float*)d_in[6];
    const float* ln2_w  = (const float*)d_in[7];
    const float* ln2_b  = (const float*)d_in[8];
    const float* fc1_w  = (const float*)d_in[9];
    const float* fc1_b  = (const float*)d_in[10];
    const float* fc2_w  = (const float*)d_in[11];
    const float* fc2_b  = (const float*)d_in[12];

    // ---- ws layout: converted weights, then big regions ----
    char* ws = (char*)d_ws;
    size_t off = 0;
    auto alloc = [&](size_t els) { void* p = ws + off; off += els * 2; return (unsigned short*)p; };
    unsigned short* qkvw_b  = alloc(3145728);
    unsigned short* projw_b = alloc(1048576);
    unsigned short* fc1w_b  = alloc(4194304);
    unsigned short* fc2w_b  = alloc(4194304);
    unsigned short* qkvb_b  = alloc(3072);
    unsigned short* projb_b = alloc(1024);
    unsigned short* fc1b_b  = alloc(4096);
    unsigned short* fc2b_b  = alloc(1024);
    off = (off + 255) & ~(size_t)255;
    unsigned short* R1 = (unsigned short*)(ws + off); off += (size_t)MROWS * 1024 * 2;          // Kb -> x1
    unsigned short* R2 = (unsigned short*)(ws + off); off += (size_t)512 * 64 * NPADV * 2;      // Vt -> h2
    unsigned short* R3 = (unsigned short*)(ws + off);                                           // fc1 chunk
    size_t rem = ws_size > off ? ws_size - off : 0;
    const int CH = rem >= (size_t)MROWS * 1024 * 2 ? 1024
                 : (rem >= (size_t)MROWS * 512 * 2 ? 512 : 256);

    // d_out (f32 [M,1024] = 75.6MB) used as scratch: half1 = Qb, half2 = h1 then obuf
    unsigned short* Qb   = (unsigned short*)d_out;
    unsigned short* h1   = Qb + (size_t)MROWS * 1024;
    unsigned short* obuf = h1;
    unsigned short* Kb = R1;
    unsigned short* Vt = R2;
    unsigned short* x1 = R1;
    unsigned short* h2 = R2;

    // weight/bias conversion (every call; graph-safe)
    conv_kernel<<<3145728 / 1024, 256, 0, stream>>>(qkv_w,  qkvw_b,  3145728);
    conv_kernel<<<1048576 / 1024, 256, 0, stream>>>(proj_w, projw_b, 1048576);
    conv_kernel<<<4194304 / 1024, 256, 0, stream>>>(fc1_w,  fc1w_b,  4194304);
    conv_kernel<<<4194304 / 1024, 256, 0, stream>>>(fc2_w,  fc2w_b,  4194304);
    conv_kernel<<<3, 256, 0, stream>>>(qkv_b,  qkvb_b,  3072);
    conv_kernel<<<1, 256, 0, stream>>>(proj_b, projb_b, 1024);
    conv_kernel<<<4, 256, 0, stream>>>(fc1_b,  fc1b_b,  4096);
    conv_kernel<<<1, 256, 0, stream>>>(fc2_b,  fc2b_b,  1024);

    const int mt = (MROWS + 127) / 128;  // 145

    // h1 = LN1(x)
    ln_kernel<true><<<MROWS, 256, 0, stream>>>(x, ln1_w, ln1_b, h1);
    // qkv GEMM -> split Qb/Kb/Vt
    gemm_bt<0><<<dim3(C3DIM / 128, mt), 256, 0, stream>>>(
        h1, qkvw_b, CDIM, qkvb_b, nullptr, Qb, Kb, Vt, CDIM, C3DIM);
    // attention -> obuf (overwrites h1; h1 dead)
    attn_kernel<<<dim3(10, BATCH * NHEAD), 256, 0, stream>>>(Qb, Kb, Vt, obuf);
    // x1 = bf16(x + obuf @ proj_w^T + proj_b)    (Kb dead)
    gemm_bt<1><<<dim3(CDIM / 128, mt), 256, 0, stream>>>(
        obuf, projw_b, CDIM, projb_b, x, x1, nullptr, nullptr, CDIM, CDIM);
    // h2 = LN2(x1)   (Vt dead)
    ln_kernel<false><<<MROWS, 256, 0, stream>>>(x1, ln2_w, ln2_b, h2);
    // MLP in hidden-chunks; fc2 accumulates f32 into d_out (Qb/obuf dead)
    for (int c0 = 0; c0 < H4DIM; c0 += CH) {
        gemm_bt<2><<<dim3(CH / 128, mt), 256, 0, stream>>>(
            h2, fc1w_b + (size_t)c0 * CDIM, CDIM, fc1b_b + c0, nullptr, R3, nullptr, nullptr, CDIM, CH);
        if (c0 == 0)
            gemm_bt<3><<<dim3(CDIM / 128, mt), 256, 0, stream>>>(
                R3, fc2w_b, H4DIM, fc2b_b, x1, d_out, nullptr, nullptr, CH, CDIM);
        else
            gemm_bt<4><<<dim3(CDIM / 128, mt), 256, 0, stream>>>(
                R3, fc2w_b + c0, H4DIM, nullptr, nullptr, d_out, nullptr, nullptr, CH, CDIM);
    }
}

// Round 5
// 1281.123 us; speedup vs baseline: 1.4553x; 1.1827x over previous
//
#include <hip/hip_runtime.h>
#include <math.h>

// ---- problem constants ----
#define BATCH  32
#define NTOK   577
#define CDIM   1024
#define C3DIM  3072
#define H4DIM  4096
#define NHEAD  16
#define MROWS  (BATCH * NTOK)   // 18464
#define NPADV  584              // 577 rounded up to 8 (V^T row pad)

typedef __bf16 bf16x8 __attribute__((ext_vector_type(8)));
typedef float  f32x4  __attribute__((ext_vector_type(4)));
typedef unsigned short u16x8 __attribute__((ext_vector_type(8)));

__device__ __forceinline__ float bf2f(unsigned short u) {
    union { unsigned int i; float f; } v; v.i = ((unsigned int)u) << 16; return v.f;
}
__device__ __forceinline__ unsigned short f2bf(float f) {
    union { float f; unsigned int i; } v; v.f = f;
    unsigned int r = v.i + 0x7FFFu + ((v.i >> 16) & 1u);
    return (unsigned short)(r >> 16);
}
__device__ __forceinline__ bf16x8 ld_bf8(const unsigned short* p) {
    return __builtin_bit_cast(bf16x8, *(const u16x8*)p);
}

// async global->LDS, 16B per lane. LDS dest = wave-uniform base + lane*16.
typedef const __attribute__((address_space(1))) unsigned int* gptr_t;
typedef __attribute__((address_space(3))) unsigned int* lptr_t;
__device__ __forceinline__ void gl2lds(const void* g, const void* l) {
    __builtin_amdgcn_global_load_lds(
        (gptr_t)(unsigned long long)g,
        (lptr_t)(unsigned int)(unsigned long long)l,
        16, 0, 0);
}

// Q pre-scale: Dh^-0.5 * log2(e), so softmax runs in exp2 domain
#define QSCALE 0.18033688011112042f

// ---------------- f32 -> bf16 convert ----------------
__global__ __launch_bounds__(256) void conv_kernel(const float* __restrict__ src,
                                                   unsigned short* __restrict__ dst, int n) {
    int i = (blockIdx.x * 256 + threadIdx.x) * 4;
    if (i < n) {
        float4 v = *(const float4*)(src + i);
        dst[i]     = f2bf(v.x);
        dst[i + 1] = f2bf(v.y);
        dst[i + 2] = f2bf(v.z);
        dst[i + 3] = f2bf(v.w);
    }
}

// ---------------- LayerNorm ----------------
template<bool F32IN>
__global__ __launch_bounds__(256) void ln_kernel(
    const void* __restrict__ X,
    const float* __restrict__ w,
    const float* __restrict__ b,
    unsigned short* __restrict__ out)
{
    const int row = blockIdx.x;
    const int t = threadIdx.x;
    float vals[4]; float s = 0.f, ss = 0.f;
#pragma unroll
    for (int i = 0; i < 4; i++) {
        int c = t + i * 256;
        float v;
        if (F32IN) v = ((const float*)X)[(size_t)row * CDIM + c];
        else       v = bf2f(((const unsigned short*)X)[(size_t)row * CDIM + c]);
        vals[i] = v; s += v; ss += v * v;
    }
#pragma unroll
    for (int off = 32; off > 0; off >>= 1) { s += __shfl_xor(s, off); ss += __shfl_xor(ss, off); }
    __shared__ float red[8];
    if ((t & 63) == 0) { red[t >> 6] = s; red[4 + (t >> 6)] = ss; }
    __syncthreads();
    s  = red[0] + red[1] + red[2] + red[3];
    ss = red[4] + red[5] + red[6] + red[7];
    float mu  = s * (1.f / CDIM);
    float var = ss * (1.f / CDIM) - mu * mu;
    float rs  = rsqrtf(var + 1e-6f);
#pragma unroll
    for (int i = 0; i < 4; i++) {
        int c = t + i * 256;
        float o = (vals[i] - mu) * rs * w[c] + b[c];
        out[(size_t)row * CDIM + c] = f2bf(o);
    }
}

// ---------------- GEMM: Out = A[M,K]bf16 @ W[N,K]bf16^T + epilogue ----------------
// OP=0: +bias, qkv split-scatter (Out=Qb *QSCALE, Out2=Kb, Out3=Vt transposed)
// OP=1: +bias, + f32 residual (Res=x), bf16 out (x1)
// OP=2: +bias, GELU, bf16 out (fc1)
// OP=3: +bias, + bf16 residual (x1), f32 out to d_out
// OP=4: f32 accumulate into d_out (no bias)
template<int OP>
__global__ __launch_bounds__(256) void gemm_bt(
    const unsigned short* __restrict__ A,
    const unsigned short* __restrict__ W, int Wstride,
    const unsigned short* __restrict__ bias,
    const void* __restrict__ Res,
    void* __restrict__ Out,
    void* __restrict__ Out2,
    void* __restrict__ Out3,
    int K, int Nout)
{
    __shared__ __align__(16) unsigned short Alds[128 * 32];
    __shared__ __align__(16) unsigned short Blds[128 * 32];
    const int tid  = threadIdx.x;
    const int lane = tid & 63, wave = tid >> 6;
    const int q = lane >> 4, l16 = lane & 15;
    const int wm = (wave & 1) << 6, wn = (wave >> 1) << 6;
    const int tileM = blockIdx.y << 7, tileN = blockIdx.x << 7;

    f32x4 acc[4][4];
#pragma unroll
    for (int i = 0; i < 4; i++)
#pragma unroll
        for (int j = 0; j < 4; j++) acc[i][j] = (f32x4){0.f, 0.f, 0.f, 0.f};

    const int srow = tid >> 2;
    const int soff = (tid & 3) << 3;
    int arow1 = tileM + srow;       if (arow1 > MROWS - 1) arow1 = MROWS - 1;
    int arow2 = tileM + srow + 64;  if (arow2 > MROWS - 1) arow2 = MROWS - 1;
    const unsigned short* Aptr  = A + (size_t)arow1 * K + soff;
    const unsigned short* Aptr2 = A + (size_t)arow2 * K + soff;
    const unsigned short* Wp    = W + (size_t)(tileN + srow) * Wstride + soff;
    const unsigned short* Wp2   = Wp + (size_t)64 * Wstride;

    for (int k0 = 0; k0 < K; k0 += 32) {
        __syncthreads();   // all reads of previous tile complete
        gl2lds(Aptr  + k0, &Alds[wave * 512]);
        gl2lds(Aptr2 + k0, &Alds[2048 + wave * 512]);
        gl2lds(Wp    + k0, &Blds[wave * 512]);
        gl2lds(Wp2   + k0, &Blds[2048 + wave * 512]);
        __syncthreads();   // drains vmcnt -> LDS populated
        bf16x8 af[4], bfr[4];
#pragma unroll
        for (int mi = 0; mi < 4; mi++) af[mi]  = ld_bf8(&Alds[(wm + mi * 16 + l16) * 32 + q * 8]);
#pragma unroll
        for (int ni = 0; ni < 4; ni++) bfr[ni] = ld_bf8(&Blds[(wn + ni * 16 + l16) * 32 + q * 8]);
#pragma unroll
        for (int mi = 0; mi < 4; mi++)
#pragma unroll
            for (int ni = 0; ni < 4; ni++)
                acc[mi][ni] = __builtin_amdgcn_mfma_f32_16x16x32_bf16(af[mi], bfr[ni], acc[mi][ni], 0, 0, 0);
    }

#pragma unroll
    for (int mi = 0; mi < 4; mi++) {
#pragma unroll
        for (int r = 0; r < 4; r++) {
            int row = tileM + wm + mi * 16 + q * 4 + r;
            if (row >= MROWS) continue;
            unsigned int bb = 0, nn = 0;
            if constexpr (OP == 0) {
                bb = ((unsigned int)row * 58154u) >> 25;   // row/577, exact for row<78766
                nn = (unsigned int)row - bb * 577u;
            }
#pragma unroll
            for (int ni = 0; ni < 4; ni++) {
                int col = tileN + wn + ni * 16 + l16;
                size_t oidx = (size_t)row * Nout + col;
                float v = acc[mi][ni][r];
                if constexpr (OP != 4) v += bf2f(bias[col]);
                if constexpr (OP == 0) {
                    int s = col >> 10, h = (col >> 6) & 15, d = col & 63;
                    size_t bh = (size_t)(bb * 16 + h);
                    if (s == 0)      ((unsigned short*)Out )[(bh * NTOK + nn) * 64 + d] = f2bf(v * QSCALE);
                    else if (s == 1) ((unsigned short*)Out2)[(bh * NTOK + nn) * 64 + d] = f2bf(v);
                    else             ((unsigned short*)Out3)[(bh * 64 + d) * NPADV + nn] = f2bf(v);
                } else if constexpr (OP == 1) {
                    v += ((const float*)Res)[oidx];
                    ((unsigned short*)Out)[oidx] = f2bf(v);
                } else if constexpr (OP == 2) {
                    v = 0.5f * v * (1.0f + erff(v * 0.70710678118654752f));
                    ((unsigned short*)Out)[oidx] = f2bf(v);
                } else if constexpr (OP == 3) {
                    v += bf2f(((const unsigned short*)Res)[oidx]);
                    ((float*)Out)[oidx] = v;
                } else {
                    ((float*)Out)[oidx] += v;
                }
            }
        }
    }
}

// ---------------- Flash attention, no-max unnormalized softmax ----------------
// Scores are O(1): bf16/LN-bounded inputs make f32 exp overflow (s>88) unreachable,
// so skip the running max / alpha rescale entirely; divide by l once at the end.
// Qb pre-scaled by QSCALE (exp2 domain). Grid: 1D 5120, XCD-swizzled so the 10
// q-tiles of one (b,h) share an XCD (flat%8 == same) for K/V L2 reuse.
__global__ __launch_bounds__(256) void attn_kernel(
    const unsigned short* __restrict__ Qb,
    const unsigned short* __restrict__ Kb,
    const unsigned short* __restrict__ Vt,
    unsigned short* __restrict__ o)
{
    const int flat = blockIdx.x;
    const int x8 = flat & 7;
    const int g = flat >> 3;
    const int qt = g % 10;
    const int bh = (g / 10) * 8 + x8;      // b*16 + h
    const int q0 = qt * 64;
    const int tid = threadIdx.x;
    const int wv = tid >> 6, lane = tid & 63;
    const int qd = lane >> 4, l16 = lane & 15;

    __shared__ __align__(16) unsigned short Ps[4][16 * 72];

    const unsigned short* Qh = Qb + (size_t)bh * NTOK * 64;
    const unsigned short* Kh = Kb + (size_t)bh * NTOK * 64;
    const unsigned short* Vh = Vt + (size_t)bh * 64 * NPADV;

    int qrow = q0 + wv * 16 + l16;
    int qr = qrow < NTOK ? qrow : NTOK - 1;
    bf16x8 qf0 = ld_bf8(Qh + (size_t)qr * 64 + qd * 8);
    bf16x8 qf1 = ld_bf8(Qh + (size_t)qr * 64 + 32 + qd * 8);

    float lsum[4];
    f32x4 Oacc[4];
#pragma unroll
    for (int r = 0; r < 4; r++) lsum[r] = 0.f;
#pragma unroll
    for (int ni = 0; ni < 4; ni++) Oacc[ni] = (f32x4){0.f, 0.f, 0.f, 0.f};

    for (int kt = 0; kt < 10; kt++) {
        const int k0 = kt * 64;
        const bool tail = (kt == 9);
        f32x4 sacc[4];
#pragma unroll
        for (int ni = 0; ni < 4; ni++) sacc[ni] = (f32x4){0.f, 0.f, 0.f, 0.f};
#pragma unroll
        for (int ni = 0; ni < 4; ni++) {
            int krow = k0 + ni * 16 + l16;
            if (krow > NTOK - 1) krow = NTOK - 1;
            const unsigned short* kp = Kh + (size_t)krow * 64 + qd * 8;
            bf16x8 b0 = ld_bf8(kp);
            bf16x8 b1 = ld_bf8(kp + 32);
            sacc[ni] = __builtin_amdgcn_mfma_f32_16x16x32_bf16(qf0, b0, sacc[ni], 0, 0, 0);
            sacc[ni] = __builtin_amdgcn_mfma_f32_16x16x32_bf16(qf1, b1, sacc[ni], 0, 0, 0);
        }

        // P = exp2(S) (Q pre-scaled into log2 domain); accumulate row-sum partials
#pragma unroll
        for (int r = 0; r < 4; r++) {
#pragma unroll
            for (int ni = 0; ni < 4; ni++) {
                float pv = exp2f(sacc[ni][r]);
                if (tail && (k0 + ni * 16 + l16 >= NTOK)) pv = 0.f;
                lsum[r] += pv;
                Ps[wv][(qd * 4 + r) * 72 + ni * 16 + l16] = f2bf(pv);
            }
        }
        // per-wave private LDS region: intra-wave DS ordering, no barrier needed

        // O += P @ V   (contract over keys; V^T rows = head dims)
#pragma unroll
        for (int kk = 0; kk < 2; kk++) {
            bf16x8 a = ld_bf8(&Ps[wv][l16 * 72 + kk * 32 + qd * 8]);
            int kchunk = k0 + kk * 32 + qd * 8;
            if (kchunk > NTOK - 1) kchunk = NTOK - 1;  // clamped chunks have P==0
#pragma unroll
            for (int ni = 0; ni < 4; ni++) {
                bf16x8 bb = ld_bf8(Vh + (size_t)(ni * 16 + l16) * NPADV + kchunk);
                Oacc[ni] = __builtin_amdgcn_mfma_f32_16x16x32_bf16(a, bb, Oacc[ni], 0, 0, 0);
            }
        }
    }

    // one cross-lane reduce at the end (sum over 16 key-columns)
#pragma unroll
    for (int r = 0; r < 4; r++)
#pragma unroll
        for (int off = 8; off > 0; off >>= 1) lsum[r] += __shfl_xor(lsum[r], off);

    const int b = bh >> 4, h = bh & 15;
#pragma unroll
    for (int r = 0; r < 4; r++) {
        int gq = q0 + wv * 16 + qd * 4 + r;
        if (gq >= NTOK) continue;
        float inv = 1.0f / lsum[r];
#pragma unroll
        for (int ni = 0; ni < 4; ni++) {
            int d = ni * 16 + l16;
            o[((size_t)b * NTOK + gq) * CDIM + (size_t)h * 64 + d] = f2bf(Oacc[ni][r] * inv);
        }
    }
}

// ---------------- launch ----------------
extern "C" void kernel_launch(void* const* d_in, const int* in_sizes, int n_in,
                              void* d_out, int out_size, void* d_ws, size_t ws_size,
                              hipStream_t stream) {
    (void)in_sizes; (void)n_in; (void)out_size;
    const float* x      = (const float*)d_in[0];
    const float* ln1_w  = (const float*)d_in[1];
    const float* ln1_b  = (const float*)d_in[2];
    const float* qkv_w  = (const float*)d_in[3];
    const float* qkv_b  = (const float*)d_in[4];
    const float* proj_w = (const float*)d_in[5];
    const float* proj_b = (const float*)d_in[6];
    const float* ln2_w  = (const float*)d_in[7];
    const float* ln2_b  = (const float*)d_in[8];
    const float* fc1_w  = (const float*)d_in[9];
    const float* fc1_b  = (const float*)d_in[10];
    const float* fc2_w  = (const float*)d_in[11];
    const float* fc2_b  = (const float*)d_in[12];

    // ---- ws layout: converted weights, then big regions ----
    char* ws = (char*)d_ws;
    size_t off = 0;
    auto alloc = [&](size_t els) { void* p = ws + off; off += els * 2; return (unsigned short*)p; };
    unsigned short* qkvw_b  = alloc(3145728);
    unsigned short* projw_b = alloc(1048576);
    unsigned short* fc1w_b  = alloc(4194304);
    unsigned short* fc2w_b  = alloc(4194304);
    unsigned short* qkvb_b  = alloc(3072);
    unsigned short* projb_b = alloc(1024);
    unsigned short* fc1b_b  = alloc(4096);
    unsigned short* fc2b_b  = alloc(1024);
    off = (off + 255) & ~(size_t)255;
    unsigned short* R1 = (unsigned short*)(ws + off); off += (size_t)MROWS * 1024 * 2;          // Kb -> x1
    unsigned short* R2 = (unsigned short*)(ws + off); off += (size_t)512 * 64 * NPADV * 2;      // Vt -> h2
    unsigned short* R3 = (unsigned short*)(ws + off);                                           // fc1 out
    size_t rem = ws_size > off ? ws_size - off : 0;
    const int CH = rem >= (size_t)MROWS * H4DIM * 2 ? H4DIM
                 : (rem >= (size_t)MROWS * 1024 * 2 ? 1024
                 : (rem >= (size_t)MROWS * 512 * 2 ? 512 : 256));

    // d_out (f32 [M,1024] = 75.6MB) used as scratch: half1 = Qb, half2 = h1 then obuf
    unsigned short* Qb   = (unsigned short*)d_out;
    unsigned short* h1   = Qb + (size_t)MROWS * 1024;
    unsigned short* obuf = h1;
    unsigned short* Kb = R1;
    unsigned short* Vt = R2;
    unsigned short* x1 = R1;
    unsigned short* h2 = R2;

    // weight/bias conversion (every call; graph-safe)
    conv_kernel<<<3145728 / 1024, 256, 0, stream>>>(qkv_w,  qkvw_b,  3145728);
    conv_kernel<<<1048576 / 1024, 256, 0, stream>>>(proj_w, projw_b, 1048576);
    conv_kernel<<<4194304 / 1024, 256, 0, stream>>>(fc1_w,  fc1w_b,  4194304);
    conv_kernel<<<4194304 / 1024, 256, 0, stream>>>(fc2_w,  fc2w_b,  4194304);
    conv_kernel<<<3, 256, 0, stream>>>(qkv_b,  qkvb_b,  3072);
    conv_kernel<<<1, 256, 0, stream>>>(proj_b, projb_b, 1024);
    conv_kernel<<<4, 256, 0, stream>>>(fc1_b,  fc1b_b,  4096);
    conv_kernel<<<1, 256, 0, stream>>>(fc2_b,  fc2b_b,  1024);

    const int mt = (MROWS + 127) / 128;  // 145

    // h1 = LN1(x)
    ln_kernel<true><<<MROWS, 256, 0, stream>>>(x, ln1_w, ln1_b, h1);
    // qkv GEMM -> split Qb/Kb/Vt
    gemm_bt<0><<<dim3(C3DIM / 128, mt), 256, 0, stream>>>(
        h1, qkvw_b, CDIM, qkvb_b, nullptr, Qb, Kb, Vt, CDIM, C3DIM);
    // attention -> obuf (overwrites h1; h1 dead)
    attn_kernel<<<5120, 256, 0, stream>>>(Qb, Kb, Vt, obuf);
    // x1 = bf16(x + obuf @ proj_w^T + proj_b)    (Kb dead)
    gemm_bt<1><<<dim3(CDIM / 128, mt), 256, 0, stream>>>(
        obuf, projw_b, CDIM, projb_b, x, x1, nullptr, nullptr, CDIM, CDIM);
    // h2 = LN2(x1)   (Vt dead)
    ln_kernel<false><<<MROWS, 256, 0, stream>>>(x1, ln2_w, ln2_b, h2);

    if (CH == H4DIM) {
        // full MLP: one fc1, one fc2 (d_out free: Qb/obuf dead)
        gemm_bt<2><<<dim3(H4DIM / 128, mt), 256, 0, stream>>>(
            h2, fc1w_b, CDIM, fc1b_b, nullptr, R3, nullptr, nullptr, CDIM, H4DIM);
        gemm_bt<3><<<dim3(CDIM / 128, mt), 256, 0, stream>>>(
            R3, fc2w_b, H4DIM, fc2b_b, x1, d_out, nullptr, nullptr, H4DIM, CDIM);
    } else {
        for (int c0 = 0; c0 < H4DIM; c0 += CH) {
            gemm_bt<2><<<dim3(CH / 128, mt), 256, 0, stream>>>(
                h2, fc1w_b + (size_t)c0 * CDIM, CDIM, fc1b_b + c0, nullptr, R3, nullptr, nullptr, CDIM, CH);
            if (c0 == 0)
                gemm_bt<3><<<dim3(CDIM / 128, mt), 256, 0, stream>>>(
                    R3, fc2w_b, H4DIM, fc2b_b, x1, d_out, nullptr, nullptr, CH, CDIM);
            else
                gemm_bt<4><<<dim3(CDIM / 128, mt), 256, 0, stream>>>(
                    R3, fc2w_b + c0, H4DIM, nullptr, nullptr, d_out, nullptr, nullptr, CH, CDIM);
        }
    }
}